// Round 15
// baseline (375.893 us; speedup 1.0000x reference)
//
#include <hip/hip_runtime.h>

#define NN 100000
#define DD 128
#define EE 1600000
#define CAP 64            // padded CSR capacity per node (deg ~ Poisson(16))
#define NGROUP 8
#define NPX (NN / NGROUP) // 12500 dst nodes per XCD group

typedef __attribute__((ext_vector_type(8))) short short8;
typedef __attribute__((ext_vector_type(4))) float f32x4;
typedef __attribute__((ext_vector_type(4))) int intv4;

__device__ __forceinline__ unsigned short f2bf(float f) {
  unsigned int u = __builtin_bit_cast(unsigned int, f);
  unsigned int r = (u + 0x7FFFu + ((u >> 16) & 1u)) >> 16;
  return (unsigned short)r;
}
__device__ __forceinline__ float bf2f(unsigned int lo16) {
  unsigned int u = lo16 << 16;
  return __builtin_bit_cast(float, u);
}

// ---------------- casts ----------------

__global__ __launch_bounds__(256) void cast_x_kernel(const float* __restrict__ x,
                                                     unsigned short* __restrict__ xb) {
  int i = blockIdx.x * 256 + threadIdx.x;  // float4 units
  if (i < NN * DD / 4) {
    float4 v = ((const float4*)x)[i];
    ushort4 o;
    o.x = f2bf(v.x); o.y = f2bf(v.y); o.z = f2bf(v.z); o.w = f2bf(v.w);
    ((ushort4*)xb)[i] = o;
  }
}

__global__ __launch_bounds__(256) void cast_w_kernel(
    const float* __restrict__ W0, const float* __restrict__ W1,
    const float* __restrict__ W2, const float* __restrict__ W3,
    const float* __restrict__ W4, const float* __restrict__ W5,
    unsigned short* __restrict__ wb) {
  int i = blockIdx.x * 256 + threadIdx.x;  // float4 units, 4096 per matrix
  if (i >= 6 * DD * DD / 4) return;
  int m = i >> 12;
  const float* Ws[6] = {W0, W1, W2, W3, W4, W5};
  float4 v = ((const float4*)Ws[m])[i & 4095];
  ushort4 o;
  o.x = f2bf(v.x); o.y = f2bf(v.y); o.z = f2bf(v.z); o.w = f2bf(v.w);
  ((ushort4*)wb)[i] = o;
}

// ---------------- padded CSR build: single pass, XCD-local by dst range ------
// R7-proven. Random 4B scatter costs ~40-64B HBM write/edge regardless of
// locality scheme (R4..R11) -- structural. Src stream load predicated on any
// dst hit (41%) to trim the read side.

__global__ __launch_bounds__(256) void fill2_kernel(const int* __restrict__ ei,
                                                    int* __restrict__ cnt,
                                                    int* __restrict__ csr) {
  const int g = blockIdx.x & (NGROUP - 1);   // XCD round-robin (R8-validated)
  const int bs = blockIdx.x >> 3;
  const int lo = g * NPX, hi = lo + NPX;
  const int tpg = (gridDim.x >> 3) * 256;    // threads per group
  const intv4* __restrict__ d4 = (const intv4*)(ei + EE);
  const intv4* __restrict__ s4 = (const intv4*)ei;
  for (int q = bs * 256 + threadIdx.x; q < EE / 4; q += tpg) {
    const intv4 d = __builtin_nontemporal_load(&d4[q]);
    const bool nx = d.x >= lo && d.x < hi;
    const bool ny = d.y >= lo && d.y < hi;
    const bool nz = d.z >= lo && d.z < hi;
    const bool nw = d.w >= lo && d.w < hi;
    if (!(nx || ny || nz || nw)) continue;
    const intv4 s = __builtin_nontemporal_load(&s4[q]);
    if (nx) {
      int slot = atomicAdd(&cnt[d.x], 1);
      if (slot < CAP) csr[(size_t)d.x * CAP + slot] = s.x;
    }
    if (ny) {
      int slot = atomicAdd(&cnt[d.y], 1);
      if (slot < CAP) csr[(size_t)d.y * CAP + slot] = s.y;
    }
    if (nz) {
      int slot = atomicAdd(&cnt[d.z], 1);
      if (slot < CAP) csr[(size_t)d.z * CAP + slot] = s.z;
    }
    if (nw) {
      int slot = atomicAdd(&cnt[d.w], 1);
      if (slot < CAP) csr[(size_t)d.w * CAP + slot] = s.w;
    }
  }
}

// ---------------- mean aggregation ----------------
// one wave per node; indices via one coalesced lane-load + full-exec __shfl
// (wave-uniform trip counts everywhere -- R6 lesson). Full rounds of 16 edges
// keep 4 independent uint4 gathers in flight per lane. At the measured ~6.8
// TB/s random-gather (L3) ceiling (R8: doubling MLP changed nothing).

__global__ __launch_bounds__(256) void agg_kernel(const unsigned short* __restrict__ hb,
                                                  const int* __restrict__ cnt,
                                                  const int* __restrict__ csr,
                                                  unsigned short* __restrict__ aggb) {
  const int node = blockIdx.x * 4 + (threadIdx.x >> 6);
  const int lane = threadIdx.x & 63;
  const int sub = lane >> 4;
  const int cl = lane & 15;
  const int n = min(cnt[node], CAP);       // wave-uniform
  const int* __restrict__ lst = csr + (size_t)node * CAP;
  const int idxreg = (lane < n) ? lst[lane] : 0;  // one coalesced load
  float acc[8] = {0.f, 0.f, 0.f, 0.f, 0.f, 0.f, 0.f, 0.f};

  int base = 0;
  for (; base + 16 <= n; base += 16) {
    int s[4];
#pragma unroll
    for (int u = 0; u < 4; ++u) s[u] = __shfl(idxreg, base + sub + 4 * u, 64);
    uint4 v[4];
#pragma unroll
    for (int u = 0; u < 4; ++u)
      v[u] = *(const uint4*)(hb + (size_t)s[u] * DD + cl * 8);
#pragma unroll
    for (int u = 0; u < 4; ++u) {
      acc[0] += bf2f(v[u].x & 0xffff);
      acc[1] += bf2f(v[u].x >> 16);
      acc[2] += bf2f(v[u].y & 0xffff);
      acc[3] += bf2f(v[u].y >> 16);
      acc[4] += bf2f(v[u].z & 0xffff);
      acc[5] += bf2f(v[u].z >> 16);
      acc[6] += bf2f(v[u].w & 0xffff);
      acc[7] += bf2f(v[u].w >> 16);
    }
  }
  if (base < n) {
    int s[4];
#pragma unroll
    for (int u = 0; u < 4; ++u)
      s[u] = __shfl(idxreg, min(base + sub + 4 * u, 63), 64);
#pragma unroll
    for (int u = 0; u < 4; ++u) {
      const int p = base + sub + 4 * u;
      if (p < n) {
        const uint4 v = *(const uint4*)(hb + (size_t)s[u] * DD + cl * 8);
        acc[0] += bf2f(v.x & 0xffff);
        acc[1] += bf2f(v.x >> 16);
        acc[2] += bf2f(v.y & 0xffff);
        acc[3] += bf2f(v.y >> 16);
        acc[4] += bf2f(v.z & 0xffff);
        acc[5] += bf2f(v.z >> 16);
        acc[6] += bf2f(v.w & 0xffff);
        acc[7] += bf2f(v.w >> 16);
      }
    }
  }
#pragma unroll
  for (int i = 0; i < 8; ++i) {
    acc[i] += __shfl_xor(acc[i], 16, 64);
    acc[i] += __shfl_xor(acc[i], 32, 64);
  }
  if (sub == 0) {
    const float inv = 1.0f / fmaxf((float)n, 1.0f);
    uint4 o;
    o.x = (unsigned int)f2bf(acc[0] * inv) | ((unsigned int)f2bf(acc[1] * inv) << 16);
    o.y = (unsigned int)f2bf(acc[2] * inv) | ((unsigned int)f2bf(acc[3] * inv) << 16);
    o.z = (unsigned int)f2bf(acc[4] * inv) | ((unsigned int)f2bf(acc[5] * inv) << 16);
    o.w = (unsigned int)f2bf(acc[6] * inv) | ((unsigned int)f2bf(acc[7] * inv) << 16);
    *(uint4*)(aggb + (size_t)node * DD + cl * 8) = o;
  }
}

// ---------------- fused dual-GEMM via MFMA bf16, W pair staged in LDS ----------
// 256 rows/block, 4 waves. R15 change: rt-OUTER loop -- each row-tile loads its
// 8 A-fragments (32 VGPR) right before use and they die at iteration end.
// R14's ct-outer form needed 128 VGPRs of A live across all 8 col-tiles; at
// VGPR_Count=88 the compiler was rematerializing A global loads per col-tile
// (up to 8x A re-read). Cost of swap: bl/br re-read from LDS 4x (~3us/call at
// 69 TB/s LDS BW) -- cheap vs 7x less A traffic.

template <int OUT_F32>
__global__ __launch_bounds__(256, 2) void lin_mfma_kernel(
    const unsigned short* __restrict__ hb, const unsigned short* __restrict__ aggb,
    const unsigned short* __restrict__ Wl, const unsigned short* __restrict__ Wr,
    const float* __restrict__ bias, void* __restrict__ outp) {
  __shared__ short8 lw[2][DD * DD / 8];  // 64 KB total
  const int t = threadIdx.x;
  const int w = t >> 6;
  const int l = t & 63;
  const int lr = l & 15;  // A-row within tile / B-col within tile
  const int kq = l >> 4;  // k-quarter (8 bf16 each)
  const int n0 = blockIdx.x * 256;

  {
    const short8* gl = (const short8*)Wl;
    const short8* gr = (const short8*)Wr;
    for (int i = t; i < DD * DD / 8; i += 256) {
      int j = i >> 4, c = i & 15;
      int dst = j * 16 + (c ^ (j & 15));
      lw[0][dst] = gl[i];
      lw[1][dst] = gr[i];
    }
  }
  __syncthreads();

#pragma unroll
  for (int rt = 0; rt < 4; ++rt) {
    int arow = n0 + w * 64 + rt * 16 + lr;
    if (arow >= NN) arow = NN - 1;  // clamp; stores guarded
    short8 ag[4], ah[4];
#pragma unroll
    for (int kk = 0; kk < 4; ++kk) {
      ag[kk] = *(const short8*)(aggb + (size_t)arow * DD + kk * 32 + kq * 8);
      ah[kk] = *(const short8*)(hb + (size_t)arow * DD + kk * 32 + kq * 8);
    }
#pragma unroll
    for (int ct = 0; ct < 8; ++ct) {
      const int j = ct * 16 + lr;
      f32x4 acc = {0.f, 0.f, 0.f, 0.f};
#pragma unroll
      for (int kk = 0; kk < 4; ++kk) {
        int c = kk * 4 + kq;
        int src = j * 16 + (c ^ (j & 15));
        acc = __builtin_amdgcn_mfma_f32_16x16x32_bf16(ag[kk], lw[0][src], acc, 0, 0, 0);
      }
#pragma unroll
      for (int kk = 0; kk < 4; ++kk) {
        int c = kk * 4 + kq;
        int src = j * 16 + (c ^ (j & 15));
        acc = __builtin_amdgcn_mfma_f32_16x16x32_bf16(ah[kk], lw[1][src], acc, 0, 0, 0);
      }
      // C layout: col = l&15, row = (l>>4)*4 + reg
      const float bv = bias[j];
#pragma unroll
      for (int r = 0; r < 4; ++r) {
        const int row = n0 + w * 64 + rt * 16 + kq * 4 + r;
        if (row < NN) {
          float v = fmaxf(acc[r] + bv, 0.f);
          if (OUT_F32)
            ((float*)outp)[(size_t)row * DD + j] = v;
          else
            ((unsigned short*)outp)[(size_t)row * DD + j] = f2bf(v);
        }
      }
    }
  }
}

// ---------------- launch ----------------

extern "C" void kernel_launch(void* const* d_in, const int* in_sizes, int n_in,
                              void* d_out, int out_size, void* d_ws, size_t ws_size,
                              hipStream_t stream) {
  const float* x = (const float*)d_in[0];
  const int* ei = (const int*)d_in[1];
  const float* W1l = (const float*)d_in[3];
  const float* b1 = (const float*)d_in[4];
  const float* W1r = (const float*)d_in[5];
  const float* W2l = (const float*)d_in[6];
  const float* b2 = (const float*)d_in[7];
  const float* W2r = (const float*)d_in[8];
  const float* W3l = (const float*)d_in[9];
  const float* b3 = (const float*)d_in[10];
  const float* W3r = (const float*)d_in[11];
  float* out = (float*)d_out;

  char* ws = (char*)d_ws;
  size_t off = 0;
  auto alloc = [&](size_t bytes) {
    void* p = ws + off;
    off += (bytes + 255) & ~(size_t)255;
    return p;
  };
  int* cnt = (int*)alloc(NN * sizeof(int));
  int* csr = (int*)alloc((size_t)NN * CAP * sizeof(int));
  unsigned short* hbA = (unsigned short*)alloc((size_t)NN * DD * 2);
  unsigned short* hbB = (unsigned short*)alloc((size_t)NN * DD * 2);
  unsigned short* aggb = (unsigned short*)alloc((size_t)NN * DD * 2);
  unsigned short* wb = (unsigned short*)alloc(6 * DD * DD * 2);

  unsigned short* w1l = wb + 0 * DD * DD;
  unsigned short* w1r = wb + 1 * DD * DD;
  unsigned short* w2l = wb + 2 * DD * DD;
  unsigned short* w2r = wb + 3 * DD * DD;
  unsigned short* w3l = wb + 4 * DD * DD;
  unsigned short* w3r = wb + 5 * DD * DD;

  // casts
  cast_x_kernel<<<(NN * DD / 4 + 255) / 256, 256, 0, stream>>>(x, hbA);
  cast_w_kernel<<<(6 * DD * DD / 4 + 255) / 256, 256, 0, stream>>>(
      W1l, W1r, W2l, W2r, W3l, W3r, wb);

  // padded CSR build (single pass)
  (void)hipMemsetAsync(cnt, 0, NN * sizeof(int), stream);
  fill2_kernel<<<NGROUP * 256, 256, 0, stream>>>(ei, cnt, csr);

  const int LIN_GRID = (NN + 255) / 256;
  // layer 1: hbA -> hbB
  agg_kernel<<<NN / 4, 256, 0, stream>>>(hbA, cnt, csr, aggb);
  lin_mfma_kernel<0><<<LIN_GRID, 256, 0, stream>>>(hbA, aggb, w1l, w1r, b1, hbB);
  // layer 2: hbB -> hbA
  agg_kernel<<<NN / 4, 256, 0, stream>>>(hbB, cnt, csr, aggb);
  lin_mfma_kernel<0><<<LIN_GRID, 256, 0, stream>>>(hbB, aggb, w2l, w2r, b2, hbA);
  // layer 3: hbA -> out (f32)
  agg_kernel<<<NN / 4, 256, 0, stream>>>(hbA, cnt, csr, aggb);
  lin_mfma_kernel<1><<<LIN_GRID, 256, 0, stream>>>(hbA, aggb, w3l, w3r, b3, out);
}

// Round 16
// 352.771 us; speedup vs baseline: 1.0655x; 1.0655x over previous
//
#include <hip/hip_runtime.h>

#define NN 100000
#define DD 128
#define EE 1600000
#define CAP 64            // padded CSR capacity per node (deg ~ Poisson(16))
#define NGROUP 8
#define NPX (NN / NGROUP) // 12500 dst nodes per XCD group

typedef __attribute__((ext_vector_type(8))) short short8;
typedef __attribute__((ext_vector_type(4))) float f32x4;
typedef __attribute__((ext_vector_type(4))) int intv4;

__device__ __forceinline__ unsigned short f2bf(float f) {
  unsigned int u = __builtin_bit_cast(unsigned int, f);
  unsigned int r = (u + 0x7FFFu + ((u >> 16) & 1u)) >> 16;
  return (unsigned short)r;
}
__device__ __forceinline__ float bf2f(unsigned int lo16) {
  unsigned int u = lo16 << 16;
  return __builtin_bit_cast(float, u);
}

// ---------------- casts ----------------

__global__ __launch_bounds__(256) void cast_x_kernel(const float* __restrict__ x,
                                                     unsigned short* __restrict__ xb) {
  int i = blockIdx.x * 256 + threadIdx.x;  // float4 units
  if (i < NN * DD / 4) {
    float4 v = ((const float4*)x)[i];
    ushort4 o;
    o.x = f2bf(v.x); o.y = f2bf(v.y); o.z = f2bf(v.z); o.w = f2bf(v.w);
    ((ushort4*)xb)[i] = o;
  }
}

__global__ __launch_bounds__(256) void cast_w_kernel(
    const float* __restrict__ W0, const float* __restrict__ W1,
    const float* __restrict__ W2, const float* __restrict__ W3,
    const float* __restrict__ W4, const float* __restrict__ W5,
    unsigned short* __restrict__ wb) {
  int i = blockIdx.x * 256 + threadIdx.x;  // float4 units, 4096 per matrix
  if (i >= 6 * DD * DD / 4) return;
  int m = i >> 12;
  const float* Ws[6] = {W0, W1, W2, W3, W4, W5};
  float4 v = ((const float4*)Ws[m])[i & 4095];
  ushort4 o;
  o.x = f2bf(v.x); o.y = f2bf(v.y); o.z = f2bf(v.z); o.w = f2bf(v.w);
  ((ushort4*)wb)[i] = o;
}

// ---------------- padded CSR build: single pass, XCD-local by dst range ------
// R7-proven. Random 4B scatter costs ~40-64B HBM write/edge regardless of
// locality scheme (R4..R11) -- structural. Src stream load predicated on any
// dst hit (41%) to trim the read side.

__global__ __launch_bounds__(256) void fill2_kernel(const int* __restrict__ ei,
                                                    int* __restrict__ cnt,
                                                    int* __restrict__ csr) {
  const int g = blockIdx.x & (NGROUP - 1);   // XCD round-robin (R8-validated)
  const int bs = blockIdx.x >> 3;
  const int lo = g * NPX, hi = lo + NPX;
  const int tpg = (gridDim.x >> 3) * 256;    // threads per group
  const intv4* __restrict__ d4 = (const intv4*)(ei + EE);
  const intv4* __restrict__ s4 = (const intv4*)ei;
  for (int q = bs * 256 + threadIdx.x; q < EE / 4; q += tpg) {
    const intv4 d = __builtin_nontemporal_load(&d4[q]);
    const bool nx = d.x >= lo && d.x < hi;
    const bool ny = d.y >= lo && d.y < hi;
    const bool nz = d.z >= lo && d.z < hi;
    const bool nw = d.w >= lo && d.w < hi;
    if (!(nx || ny || nz || nw)) continue;
    const intv4 s = __builtin_nontemporal_load(&s4[q]);
    if (nx) {
      int slot = atomicAdd(&cnt[d.x], 1);
      if (slot < CAP) csr[(size_t)d.x * CAP + slot] = s.x;
    }
    if (ny) {
      int slot = atomicAdd(&cnt[d.y], 1);
      if (slot < CAP) csr[(size_t)d.y * CAP + slot] = s.y;
    }
    if (nz) {
      int slot = atomicAdd(&cnt[d.z], 1);
      if (slot < CAP) csr[(size_t)d.z * CAP + slot] = s.z;
    }
    if (nw) {
      int slot = atomicAdd(&cnt[d.w], 1);
      if (slot < CAP) csr[(size_t)d.w * CAP + slot] = s.w;
    }
  }
}

// ---------------- mean aggregation ----------------
// one wave per node; indices via one coalesced lane-load + full-exec __shfl
// (wave-uniform trip counts everywhere -- R6 lesson). Full rounds of 16 edges
// keep 4 independent uint4 gathers in flight per lane. At the measured ~6.8
// TB/s random-gather (L3) ceiling (R8: doubling MLP changed nothing).

__global__ __launch_bounds__(256) void agg_kernel(const unsigned short* __restrict__ hb,
                                                  const int* __restrict__ cnt,
                                                  const int* __restrict__ csr,
                                                  unsigned short* __restrict__ aggb) {
  const int node = blockIdx.x * 4 + (threadIdx.x >> 6);
  const int lane = threadIdx.x & 63;
  const int sub = lane >> 4;
  const int cl = lane & 15;
  const int n = min(cnt[node], CAP);       // wave-uniform
  const int* __restrict__ lst = csr + (size_t)node * CAP;
  const int idxreg = (lane < n) ? lst[lane] : 0;  // one coalesced load
  float acc[8] = {0.f, 0.f, 0.f, 0.f, 0.f, 0.f, 0.f, 0.f};

  int base = 0;
  for (; base + 16 <= n; base += 16) {
    int s[4];
#pragma unroll
    for (int u = 0; u < 4; ++u) s[u] = __shfl(idxreg, base + sub + 4 * u, 64);
    uint4 v[4];
#pragma unroll
    for (int u = 0; u < 4; ++u)
      v[u] = *(const uint4*)(hb + (size_t)s[u] * DD + cl * 8);
#pragma unroll
    for (int u = 0; u < 4; ++u) {
      acc[0] += bf2f(v[u].x & 0xffff);
      acc[1] += bf2f(v[u].x >> 16);
      acc[2] += bf2f(v[u].y & 0xffff);
      acc[3] += bf2f(v[u].y >> 16);
      acc[4] += bf2f(v[u].z & 0xffff);
      acc[5] += bf2f(v[u].z >> 16);
      acc[6] += bf2f(v[u].w & 0xffff);
      acc[7] += bf2f(v[u].w >> 16);
    }
  }
  if (base < n) {
    int s[4];
#pragma unroll
    for (int u = 0; u < 4; ++u)
      s[u] = __shfl(idxreg, min(base + sub + 4 * u, 63), 64);
#pragma unroll
    for (int u = 0; u < 4; ++u) {
      const int p = base + sub + 4 * u;
      if (p < n) {
        const uint4 v = *(const uint4*)(hb + (size_t)s[u] * DD + cl * 8);
        acc[0] += bf2f(v.x & 0xffff);
        acc[1] += bf2f(v.x >> 16);
        acc[2] += bf2f(v.y & 0xffff);
        acc[3] += bf2f(v.y >> 16);
        acc[4] += bf2f(v.z & 0xffff);
        acc[5] += bf2f(v.z >> 16);
        acc[6] += bf2f(v.w & 0xffff);
        acc[7] += bf2f(v.w >> 16);
      }
    }
  }
#pragma unroll
  for (int i = 0; i < 8; ++i) {
    acc[i] += __shfl_xor(acc[i], 16, 64);
    acc[i] += __shfl_xor(acc[i], 32, 64);
  }
  if (sub == 0) {
    const float inv = 1.0f / fmaxf((float)n, 1.0f);
    uint4 o;
    o.x = (unsigned int)f2bf(acc[0] * inv) | ((unsigned int)f2bf(acc[1] * inv) << 16);
    o.y = (unsigned int)f2bf(acc[2] * inv) | ((unsigned int)f2bf(acc[3] * inv) << 16);
    o.z = (unsigned int)f2bf(acc[4] * inv) | ((unsigned int)f2bf(acc[5] * inv) << 16);
    o.w = (unsigned int)f2bf(acc[6] * inv) | ((unsigned int)f2bf(acc[7] * inv) << 16);
    *(uint4*)(aggb + (size_t)node * DD + cl * 8) = o;
  }
}

// ---------------- fused dual-GEMM via MFMA bf16, W pair staged in LDS ----------
// R12/R14-proven 27us/call -- a verified local optimum: R13 (Wr from global)
// 3x worse (gather on MFMA path, L2 thrash); R15 (rt-outer loop swap) 1.3x
// worse (4x LDS operand traffic). ct-outer form: B-frags loaded once per
// col-tile, A-frags may remat from L2 (cheap: A panels L2-resident).

template <int OUT_F32>
__global__ __launch_bounds__(256, 2) void lin_mfma_kernel(
    const unsigned short* __restrict__ hb, const unsigned short* __restrict__ aggb,
    const unsigned short* __restrict__ Wl, const unsigned short* __restrict__ Wr,
    const float* __restrict__ bias, void* __restrict__ outp) {
  __shared__ short8 lw[2][DD * DD / 8];  // 64 KB total
  const int t = threadIdx.x;
  const int w = t >> 6;
  const int l = t & 63;
  const int lr = l & 15;  // A-row within tile / B-col within tile
  const int kq = l >> 4;  // k-quarter (8 bf16 each)
  const int n0 = blockIdx.x * 256;

  {
    const short8* gl = (const short8*)Wl;
    const short8* gr = (const short8*)Wr;
    for (int i = t; i < DD * DD / 8; i += 256) {
      int j = i >> 4, c = i & 15;
      int dst = j * 16 + (c ^ (j & 15));
      lw[0][dst] = gl[i];
      lw[1][dst] = gr[i];
    }
  }

  short8 ag[4][4], ah[4][4];
#pragma unroll
  for (int rt = 0; rt < 4; ++rt) {
    int arow = n0 + w * 64 + rt * 16 + lr;
    if (arow >= NN) arow = NN - 1;  // clamp; stores guarded
#pragma unroll
    for (int kk = 0; kk < 4; ++kk) {
      ag[rt][kk] = *(const short8*)(aggb + (size_t)arow * DD + kk * 32 + kq * 8);
      ah[rt][kk] = *(const short8*)(hb + (size_t)arow * DD + kk * 32 + kq * 8);
    }
  }
  __syncthreads();

#pragma unroll
  for (int ct = 0; ct < 8; ++ct) {
    const int j = ct * 16 + lr;
    short8 bl[4], br[4];
#pragma unroll
    for (int kk = 0; kk < 4; ++kk) {
      int c = kk * 4 + kq;
      int src = j * 16 + (c ^ (j & 15));
      bl[kk] = lw[0][src];
      br[kk] = lw[1][src];
    }
    const float bv = bias[j];
#pragma unroll
    for (int rt = 0; rt < 4; ++rt) {
      f32x4 acc = {0.f, 0.f, 0.f, 0.f};
#pragma unroll
      for (int kk = 0; kk < 4; ++kk)
        acc = __builtin_amdgcn_mfma_f32_16x16x32_bf16(ag[rt][kk], bl[kk], acc, 0, 0, 0);
#pragma unroll
      for (int kk = 0; kk < 4; ++kk)
        acc = __builtin_amdgcn_mfma_f32_16x16x32_bf16(ah[rt][kk], br[kk], acc, 0, 0, 0);
      // C layout: col = l&15, row = (l>>4)*4 + reg
#pragma unroll
      for (int r = 0; r < 4; ++r) {
        const int row = n0 + w * 64 + rt * 16 + kq * 4 + r;
        if (row < NN) {
          float v = fmaxf(acc[r] + bv, 0.f);
          if (OUT_F32)
            ((float*)outp)[(size_t)row * DD + j] = v;
          else
            ((unsigned short*)outp)[(size_t)row * DD + j] = f2bf(v);
        }
      }
    }
  }
}

// ---------------- launch ----------------

extern "C" void kernel_launch(void* const* d_in, const int* in_sizes, int n_in,
                              void* d_out, int out_size, void* d_ws, size_t ws_size,
                              hipStream_t stream) {
  const float* x = (const float*)d_in[0];
  const int* ei = (const int*)d_in[1];
  const float* W1l = (const float*)d_in[3];
  const float* b1 = (const float*)d_in[4];
  const float* W1r = (const float*)d_in[5];
  const float* W2l = (const float*)d_in[6];
  const float* b2 = (const float*)d_in[7];
  const float* W2r = (const float*)d_in[8];
  const float* W3l = (const float*)d_in[9];
  const float* b3 = (const float*)d_in[10];
  const float* W3r = (const float*)d_in[11];
  float* out = (float*)d_out;

  char* ws = (char*)d_ws;
  size_t off = 0;
  auto alloc = [&](size_t bytes) {
    void* p = ws + off;
    off += (bytes + 255) & ~(size_t)255;
    return p;
  };
  int* cnt = (int*)alloc(NN * sizeof(int));
  int* csr = (int*)alloc((size_t)NN * CAP * sizeof(int));
  unsigned short* hbA = (unsigned short*)alloc((size_t)NN * DD * 2);
  unsigned short* hbB = (unsigned short*)alloc((size_t)NN * DD * 2);
  unsigned short* aggb = (unsigned short*)alloc((size_t)NN * DD * 2);
  unsigned short* wb = (unsigned short*)alloc(6 * DD * DD * 2);

  unsigned short* w1l = wb + 0 * DD * DD;
  unsigned short* w1r = wb + 1 * DD * DD;
  unsigned short* w2l = wb + 2 * DD * DD;
  unsigned short* w2r = wb + 3 * DD * DD;
  unsigned short* w3l = wb + 4 * DD * DD;
  unsigned short* w3r = wb + 5 * DD * DD;

  // casts
  cast_x_kernel<<<(NN * DD / 4 + 255) / 256, 256, 0, stream>>>(x, hbA);
  cast_w_kernel<<<(6 * DD * DD / 4 + 255) / 256, 256, 0, stream>>>(
      W1l, W1r, W2l, W2r, W3l, W3r, wb);

  // padded CSR build (single pass)
  (void)hipMemsetAsync(cnt, 0, NN * sizeof(int), stream);
  fill2_kernel<<<NGROUP * 256, 256, 0, stream>>>(ei, cnt, csr);

  const int LIN_GRID = (NN + 255) / 256;
  // layer 1: hbA -> hbB
  agg_kernel<<<NN / 4, 256, 0, stream>>>(hbA, cnt, csr, aggb);
  lin_mfma_kernel<0><<<LIN_GRID, 256, 0, stream>>>(hbA, aggb, w1l, w1r, b1, hbB);
  // layer 2: hbB -> hbA
  agg_kernel<<<NN / 4, 256, 0, stream>>>(hbB, cnt, csr, aggb);
  lin_mfma_kernel<0><<<LIN_GRID, 256, 0, stream>>>(hbB, aggb, w2l, w2r, b2, hbA);
  // layer 3: hbA -> out (f32)
  agg_kernel<<<NN / 4, 256, 0, stream>>>(hbA, cnt, csr, aggb);
  lin_mfma_kernel<1><<<LIN_GRID, 256, 0, stream>>>(hbA, aggb, w3l, w3r, b3, out);
}